// Round 14
// baseline (154.301 us; speedup 1.0000x reference)
//
#include <hip/hip_runtime.h>
#include <hip/hip_bf16.h>

// NT-Xent, BATCH=4096, N=8192, D=512, TEMP=0.1 — bf16 MFMA.
// Round 14: r12 structure (128x128 tile, 4 waves 2x2 of 64x64, BK=32,
// 16 waves/CU) but A-fragments loaded DIRECT FROM GLOBAL (L1/L2-hot panel),
// double-buffered in registers; only B goes through LDS (16 KB/block).
// Mechanism: r7/r12 measured LDS-BW-bound (~48 KB/block-step ~ 465 cyc);
// splitting A onto the L1/L2 pipe halves LDS bytes and runs pipes in parallel.
// loss = mean_i [ logsumexp_{j!=i} sim[i,j] - sim[i,partner(i)] ]
// acc  = mean_i [ sim[i,partner(i)] >= max_{j!=i,partner} sim[i,j] ]
// sim = (msg_n . img_n^T)/TEMP, 10x folded into msg side before bf16 cast.

#define NROWS 8192
#define BATCHD 4096
#define DIM 512
#define BM 128
#define BN 128
#define BK 32
#define NSTEP (DIM / BK)   // 16 K-steps
#define SHIFT 10.0f

typedef short bf16x8 __attribute__((ext_vector_type(8)));
typedef float f32x4 __attribute__((ext_vector_type(4)));

#define GLDS(g, l)                                                             \
    __builtin_amdgcn_global_load_lds(                                          \
        (const __attribute__((address_space(1))) void*)(g),                    \
        (__attribute__((address_space(3))) void*)(l), 16, 0, 0)

__device__ __forceinline__ unsigned f2u_ord(float f) {
    unsigned u = __float_as_uint(f);
    return (u & 0x80000000u) ? ~u : (u | 0x80000000u);
}
__device__ __forceinline__ float u2f_ord(unsigned e) {
    return (e & 0x80000000u) ? __uint_as_float(e & 0x7fffffffu) : __uint_as_float(~e);
}
__device__ __forceinline__ short f2bf(float f) {  // RNE f32 -> bf16 bits
    unsigned u = __float_as_uint(f);
    return (short)((u + 0x7fffu + ((u >> 16) & 1u)) >> 16);
}

// blocks 0..NROWS-1: msg (x10); NROWS..2*NROWS-1: img (x1).
// First 128 blocks also zero rowsum/rowmax/accum.
__global__ __launch_bounds__(64) void normalize_bf16_both(const float* __restrict__ msg,
                                                          const float* __restrict__ img,
                                                          short* __restrict__ mnb,
                                                          short* __restrict__ imb,
                                                          float* __restrict__ rowsum,
                                                          unsigned* __restrict__ rowmax,
                                                          float* __restrict__ accum) {
    if (blockIdx.x < 128) {
        const int i = blockIdx.x * 64 + threadIdx.x;
        rowsum[i] = 0.f;
        rowmax[i] = 0u;  // encodes "most negative"
        if (i < 2) accum[i] = 0.f;
    }
    int row = blockIdx.x;
    const float* in;
    short* out;
    float scale;
    if (row < NROWS) { in = msg; out = mnb; scale = 10.0f; }
    else { row -= NROWS; in = img; out = imb; scale = 1.0f; }
    const int lane = threadIdx.x;
    const float* src = in + (size_t)row * DIM + lane * 8;
    float4 v0 = *(const float4*)(src);
    float4 v1 = *(const float4*)(src + 4);
    float ss = v0.x*v0.x + v0.y*v0.y + v0.z*v0.z + v0.w*v0.w
             + v1.x*v1.x + v1.y*v1.y + v1.z*v1.z + v1.w*v1.w;
    #pragma unroll
    for (int off = 1; off < 64; off <<= 1) ss += __shfl_xor(ss, off);
    const float inv = scale / fmaxf(sqrtf(ss), 1e-8f);
    float vv[8] = {v0.x, v0.y, v0.z, v0.w, v1.x, v1.y, v1.z, v1.w};
    bf16x8 o;
    #pragma unroll
    for (int j = 0; j < 8; ++j) o[j] = f2bf(vv[j] * inv);
    *(bf16x8*)(out + (size_t)row * DIM + lane * 8) = o;
}

// A = msg_n*10 (bf16), B = img_n (bf16); row-major [8192][512].
// 128x128 tile, 4 waves (2M x 2N, per-wave 64x64), BK=32.
// B LDS per buffer: [128 rows][4 chunks of 16B], chunk-slot p of row r holds
// logical chunk p ^ ((r>>1)&3) (verified 0-conflict); A read direct global.
__global__ __launch_bounds__(256, 4) void simloss_mfma(const short* __restrict__ A,
                                                       const short* __restrict__ B,
                                                       float* __restrict__ rowsum,
                                                       unsigned* __restrict__ rowmax,
                                                       float* __restrict__ rowpos) {
    __shared__ short Bs[2][BN * BK];  // 2 x 8 KB only

    const int tid = threadIdx.x;
    const int lane = tid & 63;
    const int g = lane >> 4;     // k-chunk 0..3
    const int r16 = lane & 15;
    const int wid = tid >> 6;
    const int wr = wid >> 1;     // 0..1  (M waves, 64 rows each)
    const int wc = wid & 1;      // 0..1  (N waves, 64 cols each)

    // XCD stripes, bx-major traversal (by fastest): 4096 blocks = 64 by x 64 bx.
    const int bid = blockIdx.x;
    const int xcd = bid & 7;
    const int l = bid >> 3;          // 0..511
    const int by = xcd * 8 + (l & 7);
    const int bx = l >> 3;           // 0..63
    const int rowBase = by * BM;
    const int colBase = bx * BN;

    // --- B staging (pre-swizzled global source, linear LDS dest) ---
    const int s0 = tid, s1 = tid + 256;
    const int r0 = s0 >> 2, r1 = s1 >> 2;       // 0..63, 64..127
    const int c0 = (s0 & 3) ^ ((r0 >> 1) & 3);
    const int c1 = (s1 & 3) ^ ((r1 >> 1) & 3);
    const short* gB0 = B + (size_t)(colBase + r0) * DIM + c0 * 8;
    const short* gB1 = B + (size_t)(colBase + r1) * DIM + c1 * 8;

#define STAGE_B(b, koff)                                \
    do {                                                \
        GLDS(gB0 + (koff), &Bs[b][tid * 8]);            \
        GLDS(gB1 + (koff), &Bs[b][2048 + tid * 8]);     \
    } while (0)

    // --- A fragments direct from global: row = rowBase + wr*64 + m*16 + r16,
    //     16B at column g*8 + k; panel is L1/L2-hot across bx-blocks ---
    const short* aP = A + (size_t)(rowBase + wr * 64 + r16) * DIM + g * 8;
#define LOADA(dst, koff)                                                    \
    do {                                                                    \
        _Pragma("unroll") for (int m = 0; m < 4; ++m)                       \
            dst[m] = *(const bf16x8*)(aP + (size_t)m * 16 * DIM + (koff));  \
    } while (0)

    // B fragment read base (shorts); same XOR on read side (verified shape)
    const int swz = (r16 >> 1) & 3;
    const int bBase = (wc * 64 + r16) * BK + ((g ^ swz) * 8);

    f32x4 acc[4][4] = {};
    bf16x8 afA[4], afB[4];   // ping-pong A fragments

#define VMCNT(n) asm volatile("s_waitcnt vmcnt(" #n ")" ::: "memory")
#define BAR() __builtin_amdgcn_s_barrier()

    // STEP: per iteration 6 VMEM ops (2 B-GLDS + 4 A-loads). VMCNT(6) after
    // issuing the next 6 drains the previous 6 (incl. this step's B staging)
    // regardless of within-group ordering. Compiler auto-waits AF reg deps.
#define STEP(t, b, AF, AFN)                                                  \
    do {                                                                     \
        if ((t) < NSTEP - 1) {                                               \
            STAGE_B((b) ^ 1, ((t) + 1) * BK);                                \
            LOADA(AFN, ((t) + 1) * BK);                                      \
            VMCNT(6);                                                        \
        } else {                                                             \
            VMCNT(0);                                                        \
        }                                                                    \
        BAR();                                                               \
        bf16x8 bfr[4];                                                       \
        _Pragma("unroll") for (int n = 0; n < 4; ++n)                        \
            bfr[n] = *(const bf16x8*)&Bs[b][bBase + n * 16 * BK];            \
        __builtin_amdgcn_s_setprio(1);                                       \
        _Pragma("unroll") for (int m = 0; m < 4; ++m)                        \
            _Pragma("unroll") for (int n = 0; n < 4; ++n)                    \
                acc[m][n] = __builtin_amdgcn_mfma_f32_16x16x32_bf16(         \
                    AF[m], bfr[n], acc[m][n], 0, 0, 0);                      \
        __builtin_amdgcn_s_setprio(0);                                       \
        BAR();                                                               \
    } while (0)

    // prologue: stage B tile 0, load A frags 0 (6 VMEM in flight)
    STAGE_B(0, 0);
    LOADA(afA, 0);

    for (int j = 0; j < NSTEP / 2; ++j) {
        STEP(2 * j, 0, afA, afB);
        STEP(2 * j + 1, 1, afB, afA);
    }

    // ---- fused epilogue ----
    // C/D layout: col = lane&15 (r16), row = g*4 + reg  [m89 verified]
    __syncthreads();
    float* ssum = (float*)&Bs[0][0];  // 128*2 floats
    float* smx = ssum + 256;          // 128*2 floats
    const int baseRow = rowBase + wr * 64 + g * 4;
    const int baseCol = colBase + wc * 64 + r16;
    #pragma unroll
    for (int m = 0; m < 4; ++m) {
        #pragma unroll
        for (int reg = 0; reg < 4; ++reg) {
            const int i = baseRow + m * 16 + reg;
            const int partner = i ^ BATCHD;
            float sum = 0.f, mx = -1e30f;
            #pragma unroll
            for (int n = 0; n < 4; ++n) {
                const int j = baseCol + n * 16;
                const float s = acc[m][n][reg];
                const bool isDiag = (j == i);
                const bool isPos = (j == partner);
                float e = __expf(s - SHIFT);
                if (isDiag) e = 0.f;
                sum += e;
                if (!isDiag && !isPos) mx = fmaxf(mx, s);
                if (isPos) rowpos[i] = s;  // exactly one writer grid-wide
            }
            #pragma unroll
            for (int off = 1; off < 16; off <<= 1) {
                sum += __shfl_xor(sum, off);
                mx = fmaxf(mx, __shfl_xor(mx, off));
            }
            if (r16 == 0) {
                const int rloc = wr * 64 + m * 16 + g * 4 + reg;
                ssum[rloc * 2 + wc] = sum;
                smx[rloc * 2 + wc] = mx;
            }
        }
    }
    __syncthreads();
    // combine the 2 column-waves' partials: one atomic pair per row per block
    if (tid < BM) {
        const float s = ssum[tid * 2 + 0] + ssum[tid * 2 + 1];
        const float mx = fmaxf(smx[tid * 2 + 0], smx[tid * 2 + 1]);
        const int i = rowBase + tid;
        atomicAdd(&rowsum[i], s);
        atomicMax(&rowmax[i], f2u_ord(mx));
    }
#undef STAGE_B
#undef LOADA
#undef STEP
#undef VMCNT
#undef BAR
}

// 32 blocks x 256 threads: one row per thread, block-reduce, atomic combine.
__global__ __launch_bounds__(256) void finalize_partial(const float* __restrict__ rowsum,
                                                        const unsigned* __restrict__ rowmax,
                                                        const float* __restrict__ rowpos,
                                                        float* __restrict__ accum) {
    const int tid = threadIdx.x;
    const int i = blockIdx.x * 256 + tid;
    const float lse = SHIFT + logf(rowsum[i]);
    const float pos = rowpos[i];
    float lossAcc = lse - pos;
    float hitAcc = (pos >= u2f_ord(rowmax[i])) ? 1.f : 0.f;
    __shared__ float sl[256], sa[256];
    sl[tid] = lossAcc; sa[tid] = hitAcc;
    __syncthreads();
    for (int s = 128; s > 0; s >>= 1) {
        if (tid < s) { sl[tid] += sl[tid + s]; sa[tid] += sa[tid + s]; }
        __syncthreads();
    }
    if (tid == 0) {
        atomicAdd(&accum[0], sl[0]);
        atomicAdd(&accum[1], sa[0]);
    }
}

__global__ void finalize_write(const float* __restrict__ accum, float* __restrict__ out) {
    if (threadIdx.x == 0) {
        out[0] = accum[0] / (float)NROWS;
        out[1] = accum[1] / (float)NROWS;
    }
}

extern "C" void kernel_launch(void* const* d_in, const int* in_sizes, int n_in,
                              void* d_out, int out_size, void* d_ws, size_t ws_size,
                              hipStream_t stream) {
    const float* msg = (const float*)d_in[0];
    const float* img = (const float*)d_in[1];
    float* out = (float*)d_out;

    char* ws = (char*)d_ws;
    const size_t matBytes = (size_t)NROWS * DIM * sizeof(short);  // 8 MB
    short* mnb = (short*)ws;
    short* imb = (short*)(ws + matBytes);
    float* rowsum = (float*)(ws + 2 * matBytes);
    unsigned* rowmax = (unsigned*)(ws + 2 * matBytes + NROWS * sizeof(float));
    float* rowpos = (float*)(ws + 2 * matBytes + 2 * NROWS * sizeof(float));
    float* accum = (float*)(ws + 2 * matBytes + 3 * NROWS * sizeof(float));

    normalize_bf16_both<<<2 * NROWS, 64, 0, stream>>>(msg, img, mnb, imb,
                                                      rowsum, rowmax, accum);

    simloss_mfma<<<(NROWS / BM) * (NROWS / BN), 256, 0, stream>>>(mnb, imb, rowsum,
                                                                  rowmax, rowpos);

    finalize_partial<<<NROWS / 256, 256, 0, stream>>>(rowsum, rowmax, rowpos, accum);
    finalize_write<<<1, 64, 0, stream>>>(accum, out);
}